// Round 5
// baseline (68.655 us; speedup 1.0000x reference)
//
#include <hip/hip_runtime.h>

#define VOCAB 100000
#define D     300
#define B     256
#define L     1000
#define H     512
#define C     5

#define D4    (D / 4)      // 75 float4 per embedding row
#define NG    8            // row groups per block
#define GL    80           // lanes per row group (75 active)
#define RPG   (L / NG)     // 125 rows per group
#define NT    (NG * GL)    // 640 threads = 10 waves
#define KS1   (D / 4)      // 75: layer-1 K-slice
#define KS2   (H / 4)      // 128: layer-2 K-slice

// ---------------------------------------------------------------------------
// ONE kernel: per-block (per-document) gather-sum -> mean -> 3-layer MLP.
// grid = B = 256 blocks (1/CU), block = 640 threads.
// launch_bounds(640,3): VGPR cap ~170 (vs 44 in R4) so the compiler can keep
// batches of independent loads in flight instead of serializing each load.
// ---------------------------------------------------------------------------
__global__ __launch_bounds__(NT, 3) void dan_fused_kernel(
    const float* __restrict__ emb, const int* __restrict__ docs,
    const int* __restrict__ dlen,
    const float* __restrict__ W1, const float* __restrict__ b1,
    const float* __restrict__ W2, const float* __restrict__ b2,
    const float* __restrict__ W3, const float* __restrict__ b3,
    float* __restrict__ out) {
  const int b = blockIdx.x;
  const int t = threadIdx.x;

  __shared__ int    sidx[L];          // 4000 B
  __shared__ float4 sred[NG][D4];     // 9600 B
  __shared__ float4 s_in4[D4];        // 1200 B (viewed as float[D])
  __shared__ float  s_h1[H];          // 2048 B
  __shared__ float  s_h2[H];          // 2048 B
  __shared__ float  s_comb[4][H];     // 8192 B
  __shared__ float  s_len;

  // Stage indices as int4 (1000 ints = 250 int4, 16B-aligned since b*L*4
  // is a multiple of 16).
  if (t < L / 4)
    reinterpret_cast<int4*>(sidx)[t] =
        reinterpret_cast<const int4*>(docs + (size_t)b * L)[t];
  if (t == NT - 1) s_len = (float)dlen[b];
  __syncthreads();

  // ---- Gather + sum: group g sums rows [g*RPG, (g+1)*RPG). ----
  // Chunks of 5 independent row loads; outer unroll 2 -> ~10 loads in flight.
  const int g = t / GL;
  const int lane = t - g * GL;
  if (lane < D4) {
    float ax = 0.f, ay = 0.f, az = 0.f, aw = 0.f;
    const int base = g * RPG;
#pragma unroll 2
    for (int i = 0; i < RPG; i += 5) {
      const float4 v0 =
          reinterpret_cast<const float4*>(emb + (size_t)sidx[base + i + 0] * D)[lane];
      const float4 v1 =
          reinterpret_cast<const float4*>(emb + (size_t)sidx[base + i + 1] * D)[lane];
      const float4 v2 =
          reinterpret_cast<const float4*>(emb + (size_t)sidx[base + i + 2] * D)[lane];
      const float4 v3 =
          reinterpret_cast<const float4*>(emb + (size_t)sidx[base + i + 3] * D)[lane];
      const float4 v4 =
          reinterpret_cast<const float4*>(emb + (size_t)sidx[base + i + 4] * D)[lane];
      ax += v0.x; ay += v0.y; az += v0.z; aw += v0.w;
      ax += v1.x; ay += v1.y; az += v1.z; aw += v1.w;
      ax += v2.x; ay += v2.y; az += v2.z; aw += v2.w;
      ax += v3.x; ay += v3.y; az += v3.z; aw += v3.w;
      ax += v4.x; ay += v4.y; az += v4.z; aw += v4.w;
    }
    sred[g][lane] = make_float4(ax, ay, az, aw);
  }
  __syncthreads();

  // ---- Reduce 8 groups, divide by len ----
  if (t < D4) {
    float ax = 0.f, ay = 0.f, az = 0.f, aw = 0.f;
#pragma unroll
    for (int gg = 0; gg < NG; ++gg) {
      const float4 v = sred[gg][t];
      ax += v.x; ay += v.y; az += v.z; aw += v.w;
    }
    const float inv = 1.f / s_len;
    s_in4[t] = make_float4(ax * inv, ay * inv, az * inv, aw * inv);
  }
  __syncthreads();

  const float* s_in = reinterpret_cast<const float*>(s_in4);
  const int cg = t & 127;             // column group: 4 consecutive cols
  const int ks = (t >> 7) & 3;        // K-slice

  // ---- Layer 1: h1 = relu(avg @ W1 + b1), K=300 split 4x75, chunks of 15 --
  if (t < 512) {
    float ax = 0.f, ay = 0.f, az = 0.f, aw = 0.f;
    const int k0 = ks * KS1;
#pragma unroll 1
    for (int i = 0; i < KS1; i += 15) {
      float4 w[15];
#pragma unroll
      for (int j = 0; j < 15; ++j)
        w[j] = *reinterpret_cast<const float4*>(&W1[(k0 + i + j) * H + 4 * cg]);
#pragma unroll
      for (int j = 0; j < 15; ++j) {
        const float x = s_in[k0 + i + j];
        ax += x * w[j].x; ay += x * w[j].y; az += x * w[j].z; aw += x * w[j].w;
      }
    }
    *reinterpret_cast<float4*>(&s_comb[ks][4 * cg]) =
        make_float4(ax, ay, az, aw);
  }
  __syncthreads();
  if (t < H) {
    const float v =
        s_comb[0][t] + s_comb[1][t] + s_comb[2][t] + s_comb[3][t] + b1[t];
    s_h1[t] = fmaxf(v, 0.f);
  }
  __syncthreads();

  // ---- Layer 2: h2 = relu(h1 @ W2 + b2), K=512 split 4x128, chunks of 16 --
  if (t < 512) {
    float ax = 0.f, ay = 0.f, az = 0.f, aw = 0.f;
    const int k0 = ks * KS2;
#pragma unroll 1
    for (int i = 0; i < KS2; i += 16) {
      float4 w[16];
#pragma unroll
      for (int j = 0; j < 16; ++j)
        w[j] = *reinterpret_cast<const float4*>(&W2[(k0 + i + j) * H + 4 * cg]);
#pragma unroll
      for (int j = 0; j < 16; ++j) {
        const float x = s_h1[k0 + i + j];
        ax += x * w[j].x; ay += x * w[j].y; az += x * w[j].z; aw += x * w[j].w;
      }
    }
    *reinterpret_cast<float4*>(&s_comb[ks][4 * cg]) =
        make_float4(ax, ay, az, aw);
  }
  __syncthreads();
  if (t < H) {
    const float v =
        s_comb[0][t] + s_comb[1][t] + s_comb[2][t] + s_comb[3][t] + b2[t];
    s_h2[t] = fmaxf(v, 0.f);
  }
  __syncthreads();

  // ---- Head: out = h2 @ W3 + b3; wave w (<C) computes class w ----
  const int wv = t >> 6;
  const int ln = t & 63;
  if (wv < C) {
    float a = 0.f;
#pragma unroll
    for (int i = 0; i < H / 64; ++i) {
      const int h = i * 64 + ln;
      a += s_h2[h] * W3[h * C + wv];
    }
#pragma unroll
    for (int off = 32; off > 0; off >>= 1) a += __shfl_down(a, off);
    if (ln == 0) out[b * C + wv] = a + b3[wv];
  }
}

// ---------------------------------------------------------------------------
extern "C" void kernel_launch(void* const* d_in, const int* in_sizes, int n_in,
                              void* d_out, int out_size, void* d_ws,
                              size_t ws_size, hipStream_t stream) {
  const float* emb  = (const float*)d_in[0];
  const float* W1   = (const float*)d_in[1];
  const float* b1   = (const float*)d_in[2];
  const float* W2   = (const float*)d_in[3];
  const float* b2   = (const float*)d_in[4];
  const float* W3   = (const float*)d_in[5];
  const float* b3   = (const float*)d_in[6];
  const int*   docs = (const int*)d_in[7];
  const int*   dlen = (const int*)d_in[8];
  float* out = (float*)d_out;

  dan_fused_kernel<<<B, NT, 0, stream>>>(emb, docs, dlen, W1, b1, W2, b2, W3,
                                         b3, out);
}